// Round 6
// baseline (22.205 us; speedup 1.0000x reference)
//
#include <hip/hip_runtime.h>

#define BB 8192
#define TT 512
#define SEQF 2560      // floats per sequence (512*5)
#define WLDS 1280      // float4 slots per wave (2 seqs * 640)

__device__ __forceinline__ float rfl(float x) {
    return __int_as_float(__builtin_amdgcn_readfirstlane(__float_as_int(x)));
}

// Wave = 2 sequences. Coalesced global->reg (20x dwordx4, 1KB/instr), XOR-swizzled
// scatter to per-wave LDS, conflict-free chunk read-back. Lane: seq = lane&1,
// chunk = lane>>1, 16 timesteps. Shared parity-preserving 5-level suffix tree.
__global__ __launch_bounds__(128, 4) void crf_fused(const float* __restrict__ feats,
                                                    const float* __restrict__ trans,
                                                    float* __restrict__ out) {
    __shared__ __align__(16) float4 sm[2 * WLDS];   // 40960 B -> 4 blocks/CU

    const int tid  = threadIdx.x;
    const int lane = tid & 63;
    const int wv   = tid >> 6;
    const int s0   = (blockIdx.x * 2 + wv) * 2;

    float4* wb = &sm[wv * WLDS];

    // ---- coalesced loads: 20 float4/lane, issued before anything else ----
    const float4* gp = (const float4*)(feats + (size_t)s0 * SEQF);
    float4 h[20];
    #pragma unroll
    for (int k = 0; k < 20; ++k) h[k] = gp[k * 64 + lane];   // 2 seqs, 640 f4 each
    __builtin_amdgcn_sched_barrier(0);   // pin all loads first (max queue depth)

    // ---- uniform transition factors -> SGPRs ----
    const float E00=rfl(__expf(trans[0])),  E01=rfl(__expf(trans[1])),  E02=rfl(__expf(trans[2]));
    const float E10=rfl(__expf(trans[5])),  E11=rfl(__expf(trans[6])),  E12=rfl(__expf(trans[7]));
    const float E20=rfl(__expf(trans[10])), E21=rfl(__expf(trans[11])), E22=rfl(__expf(trans[12]));
    const float C0 =rfl(__expf(trans[3])),  C1 =rfl(__expf(trans[8])),  C2 =rfl(__expf(trans[13]));
    const float S0 =rfl(__expf(trans[20])), S1 =rfl(__expf(trans[21])), S2 =rfl(__expf(trans[22]));

    // ---- swizzled LDS scatter (compiler drains vmcnt progressively) ----
    // global float4 index within wave: G = k*64 + lane; seq s = G/640,
    // seq-local g = G%640; owner chunk c = g/20, slot j = g%20.
    // phys = j*64 + ((2c+s) ^ (j&7))  -- involutive, ~2-way banks both sides.
    #pragma unroll
    for (int k = 0; k < 20; ++k) {
        int G = k * 64 + lane;
        int s = G >> 9;            // /640 -> 0 or 1 for G<1280... use exact: G/640
        s = G / 640;
        int g = G - s * 640;
        int c = g / 20;
        int j = g - c * 20;
        wb[j * 64 + (((c << 1) + s) ^ (j & 7))] = h[k];
    }
    __builtin_amdgcn_sched_barrier(0);

    // ---- conflict-free chunk read-back: lane l <-> (c=l>>1, s=l&1) ----
    float4 q[20];
    #pragma unroll
    for (int j = 0; j < 20; ++j)
        q[j] = wb[j * 64 + (lane ^ (j & 7))];

    // first-step factor: chunk 0 (lanes 0,1) starts from the START column
    const bool c0 = (lane >> 1) == 0;
    const float G00 = c0 ? C0 : E00, G01 = c0 ? C0 : E01, G02 = c0 ? C0 : E02;
    const float G10 = c0 ? C1 : E10, G11 = c0 ? C1 : E11, G12 = c0 ? C1 : E12;
    const float G20 = c0 ? C2 : E20, G21 = c0 ? C2 : E21, G22 = c0 ? C2 : E22;

#define CRF_STEP(FA, FB, FC) do {                                   \
        float e0 = __expf(FA), e1 = __expf(FB), e2 = __expf(FC);    \
        float N00 = e0 * (E00*M00 + E01*M10 + E02*M20);             \
        float N01 = e0 * (E00*M01 + E01*M11 + E02*M21);             \
        float N02 = e0 * (E00*M02 + E01*M12 + E02*M22);             \
        float N10 = e1 * (E10*M00 + E11*M10 + E12*M20);             \
        float N11 = e1 * (E10*M01 + E11*M11 + E12*M21);             \
        float N12 = e1 * (E10*M02 + E11*M12 + E12*M22);             \
        float N20 = e2 * (E20*M00 + E21*M10 + E22*M20);             \
        float N21 = e2 * (E20*M01 + E21*M11 + E22*M21);             \
        float N22 = e2 * (E20*M02 + E21*M12 + E22*M22);             \
        M00=N00; M01=N01; M02=N02;                                  \
        M10=N10; M11=N11; M12=N12;                                  \
        M20=N20; M21=N21; M22=N22;                                  \
    } while (0)

#define CRF_RENORM() do {                                           \
        float mx = fmaxf(fmaxf(fmaxf(M00,M01), fmaxf(M02,M10)),     \
                         fmaxf(fmaxf(M11,M12), fmaxf(fmaxf(M20,M21),M22))); \
        mx = fmaxf(mx, 1e-30f);                                     \
        int ee = (int)((__float_as_uint(mx) >> 23) & 0xffu) - 127;  \
        float sc = __uint_as_float((unsigned)(127 - ee) << 23);     \
        ls += (float)ee;                                            \
        M00*=sc; M01*=sc; M02*=sc;                                  \
        M10*=sc; M11*=sc; M12*=sc;                                  \
        M20*=sc; M21*=sc; M22*=sc;                                  \
    } while (0)

#define TREE_LEVEL(D, RN) do {                                      \
        float P00=__shfl_down(M00,D), P01=__shfl_down(M01,D), P02=__shfl_down(M02,D); \
        float P10=__shfl_down(M10,D), P11=__shfl_down(M11,D), P12=__shfl_down(M12,D); \
        float P20=__shfl_down(M20,D), P21=__shfl_down(M21,D), P22=__shfl_down(M22,D); \
        float Pls=__shfl_down(ls, D);                               \
        float N00 = P00*M00 + P01*M10 + P02*M20;                    \
        float N01 = P00*M01 + P01*M11 + P02*M21;                    \
        float N02 = P00*M02 + P01*M12 + P02*M22;                    \
        float N10 = P10*M00 + P11*M10 + P12*M20;                    \
        float N11 = P10*M01 + P11*M11 + P12*M21;                    \
        float N12 = P10*M02 + P11*M12 + P12*M22;                    \
        float N20 = P20*M00 + P21*M10 + P22*M20;                    \
        float N21 = P20*M01 + P21*M11 + P22*M21;                    \
        float N22 = P20*M02 + P21*M12 + P22*M22;                    \
        M00=N00; M01=N01; M02=N02; M10=N10; M11=N11; M12=N12;       \
        M20=N20; M21=N21; M22=N22;                                  \
        ls += Pls;                                                  \
        if (RN) CRF_RENORM();                                       \
    } while (0)

    float M00, M01, M02, M10, M11, M12, M20, M21, M22;
    float ls = 0.0f;

    {   // t0: M = D(e) * G
        float e0 = __expf(q[0].x), e1 = __expf(q[0].y), e2 = __expf(q[0].z);
        M00 = e0*G00; M01 = e0*G01; M02 = e0*G02;
        M10 = e1*G10; M11 = e1*G11; M12 = e1*G12;
        M20 = e2*G20; M21 = e2*G21; M22 = e2*G22;
    }
    CRF_STEP(q[1].y,  q[1].z,  q[1].w);    // t1
    CRF_STEP(q[2].z,  q[2].w,  q[3].x);    // t2
    CRF_STEP(q[3].w,  q[4].x,  q[4].y);    // t3
    CRF_STEP(q[5].x,  q[5].y,  q[5].z);    // t4
    CRF_STEP(q[6].y,  q[6].z,  q[6].w);    // t5
    CRF_STEP(q[7].z,  q[7].w,  q[8].x);    // t6
    CRF_STEP(q[8].w,  q[9].x,  q[9].y);    // t7
    CRF_RENORM();
    CRF_STEP(q[10].x, q[10].y, q[10].z);   // t8
    CRF_STEP(q[11].y, q[11].z, q[11].w);   // t9
    CRF_STEP(q[12].z, q[12].w, q[13].x);   // t10
    CRF_STEP(q[13].w, q[14].x, q[14].y);   // t11
    CRF_STEP(q[15].x, q[15].y, q[15].z);   // t12
    CRF_STEP(q[16].y, q[16].z, q[16].w);   // t13
    CRF_STEP(q[17].z, q[17].w, q[18].x);   // t14
    CRF_STEP(q[18].w, q[19].x, q[19].y);   // t15
    CRF_RENORM();

    // shared tree: even lanes = seq A, odd lanes = seq B (parity-preserving D)
    TREE_LEVEL(2, 0);
    TREE_LEVEL(4, 1);
    TREE_LEVEL(8, 0);
    TREE_LEVEL(16, 1);
    TREE_LEVEL(32, 1);

    float r = S0*M00 + S1*M10 + S2*M20;
    float res = __logf(r) + ls * 0.69314718055994531f;
    if ((lane >> 1) == 0) out[s0 + (lane & 1)] = res;   // lanes 0,1

#undef CRF_STEP
#undef CRF_RENORM
#undef TREE_LEVEL
}

extern "C" void kernel_launch(void* const* d_in, const int* in_sizes, int n_in,
                              void* d_out, int out_size, void* d_ws, size_t ws_size,
                              hipStream_t stream) {
    const float* feats = (const float*)d_in[0];
    const float* trans = (const float*)d_in[1];
    float* out = (float*)d_out;
    (void)d_ws; (void)ws_size;

    crf_fused<<<BB / 4, 128, 0, stream>>>(feats, trans, out);
}

// Round 7
// 19.592 us; speedup vs baseline: 1.1334x; 1.1334x over previous
//
#include <hip/hip_runtime.h>

#define BB 8192
#define SEQF 2560      // floats per sequence (512*5)

typedef float v2f __attribute__((ext_vector_type(2)));

__device__ __forceinline__ float rfl(float x) {
    return __int_as_float(__builtin_amdgcn_readfirstlane(__float_as_int(x)));
}
__device__ __forceinline__ v2f vsplat(float x) { return (v2f){x, x}; }

// Wave = 2 sequences: lanes 0-31 scan seq A, lanes 32-63 scan seq B.
// Lane: 16 timesteps (320B contiguous, direct scattered dwordx4 loads).
// State: 3x3 transfer matrix as 3 packed column-pairs (v_pk_*_f32) + scalar col2.
// Bias e^-2 folded into E/C (exactly compensated) -> no mid-step renorms.
__global__ __launch_bounds__(128, 4) void crf_fused(const float* __restrict__ feats,
                                                    const float* __restrict__ trans,
                                                    float* __restrict__ out) {
    const int tid  = threadIdx.x;
    const int lane = tid & 63;
    const int half = lane >> 5;      // which sequence of the pair
    const int cpos = lane & 31;      // chunk index within the sequence
    const int wv   = tid >> 6;
    const int s0   = (blockIdx.x * 2 + wv) * 2;

    // ---- issue ALL 20 loads up front (contiguous 320 B per lane) ----
    const float4* p = (const float4*)(feats + (size_t)(s0 + half) * SEQF) + cpos * 20;
    float4 q0 =p[0],  q1 =p[1],  q2 =p[2],  q3 =p[3],  q4 =p[4];
    float4 q5 =p[5],  q6 =p[6],  q7 =p[7],  q8 =p[8],  q9 =p[9];
    float4 q10=p[10], q11=p[11], q12=p[12], q13=p[13], q14=p[14];
    float4 q15=p[15], q16=p[16], q17=p[17], q18=p[18], q19=p[19];
    __builtin_amdgcn_sched_barrier(0);   // pin loads first (max queue depth)

    // ---- uniform transition factors -> SGPRs; bias e^-2 folded in (exact comp later) ----
    const float BIAS = 0.13533528323661270f;   // e^-2
    const float E00=rfl(__expf(trans[0])*BIAS),  E01=rfl(__expf(trans[1])*BIAS),  E02=rfl(__expf(trans[2])*BIAS);
    const float E10=rfl(__expf(trans[5])*BIAS),  E11=rfl(__expf(trans[6])*BIAS),  E12=rfl(__expf(trans[7])*BIAS);
    const float E20=rfl(__expf(trans[10])*BIAS), E21=rfl(__expf(trans[11])*BIAS), E22=rfl(__expf(trans[12])*BIAS);
    const float C0 =rfl(__expf(trans[3])*BIAS),  C1 =rfl(__expf(trans[8])*BIAS),  C2 =rfl(__expf(trans[13])*BIAS);
    const float S0 =rfl(__expf(trans[20])), S1 =rfl(__expf(trans[21])), S2 =rfl(__expf(trans[22]));

    const v2f E00p=vsplat(E00), E01p=vsplat(E01), E02p=vsplat(E02);
    const v2f E10p=vsplat(E10), E11p=vsplat(E11), E12p=vsplat(E12);
    const v2f E20p=vsplat(E20), E21p=vsplat(E21), E22p=vsplat(E22);

    // first-step factor: chunk 0 of each sequence starts from the START column
    const bool c0 = (cpos == 0);
    const v2f GA0 = c0 ? vsplat(C0) : (v2f){E00, E01};
    const v2f GA1 = c0 ? vsplat(C1) : (v2f){E10, E11};
    const v2f GA2 = c0 ? vsplat(C2) : (v2f){E20, E21};
    const float GB0 = c0 ? C0 : E02;
    const float GB1 = c0 ? C1 : E12;
    const float GB2 = c0 ? C2 : E22;

    // state: MA_i = (M_i0, M_i1) packed; MB_i = M_i2
    v2f MA0, MA1, MA2;
    float MB0, MB1, MB2;
    float ls = 0.0f;

#define CRF_STEP(FA, FB, FC) do {                                   \
        float e0 = __expf(FA), e1 = __expf(FB), e2 = __expf(FC);    \
        v2f NA0 = vsplat(e0) * (E00p*MA0 + E01p*MA1 + E02p*MA2);    \
        v2f NA1 = vsplat(e1) * (E10p*MA0 + E11p*MA1 + E12p*MA2);    \
        v2f NA2 = vsplat(e2) * (E20p*MA0 + E21p*MA1 + E22p*MA2);    \
        float NB0 = e0 * (E00*MB0 + E01*MB1 + E02*MB2);             \
        float NB1 = e1 * (E10*MB0 + E11*MB1 + E12*MB2);             \
        float NB2 = e2 * (E20*MB0 + E21*MB1 + E22*MB2);             \
        MA0=NA0; MA1=NA1; MA2=NA2; MB0=NB0; MB1=NB1; MB2=NB2;       \
    } while (0)

    // exact power-of-two renorm; ls counts the exponent (units of ln2)
#define CRF_RENORM() do {                                           \
        v2f mp = __builtin_elementwise_max(__builtin_elementwise_max(MA0, MA1), MA2); \
        float mm = fmaxf(fmaxf(mp.x, mp.y), fmaxf(fmaxf(MB0, MB1), MB2)); \
        mm = fmaxf(mm, 1e-30f);                                     \
        int ee = (int)((__float_as_uint(mm) >> 23) & 0xffu) - 127;  \
        float sc = __uint_as_float((unsigned)(127 - ee) << 23);     \
        ls += (float)ee;                                            \
        v2f scp = vsplat(sc);                                       \
        MA0*=scp; MA1*=scp; MA2*=scp; MB0*=sc; MB1*=sc; MB2*=sc;    \
    } while (0)

    // suffix-scan level: P = lane+D (later in time); M <- P * M
#define TREE_LEVEL(D, RN) do {                                      \
        v2f PA0, PA1, PA2;                                          \
        PA0.x=__shfl_down(MA0.x,D); PA0.y=__shfl_down(MA0.y,D);     \
        PA1.x=__shfl_down(MA1.x,D); PA1.y=__shfl_down(MA1.y,D);     \
        PA2.x=__shfl_down(MA2.x,D); PA2.y=__shfl_down(MA2.y,D);     \
        float PB0=__shfl_down(MB0,D), PB1=__shfl_down(MB1,D), PB2=__shfl_down(MB2,D); \
        float Pls=__shfl_down(ls, D);                               \
        v2f NA0 = vsplat(PA0.x)*MA0 + vsplat(PA0.y)*MA1 + vsplat(PB0)*MA2; \
        v2f NA1 = vsplat(PA1.x)*MA0 + vsplat(PA1.y)*MA1 + vsplat(PB1)*MA2; \
        v2f NA2 = vsplat(PA2.x)*MA0 + vsplat(PA2.y)*MA1 + vsplat(PB2)*MA2; \
        float NB0 = PA0.x*MB0 + PA0.y*MB1 + PB0*MB2;                \
        float NB1 = PA1.x*MB0 + PA1.y*MB1 + PB1*MB2;                \
        float NB2 = PA2.x*MB0 + PA2.y*MB1 + PB2*MB2;                \
        MA0=NA0; MA1=NA1; MA2=NA2; MB0=NB0; MB1=NB1; MB2=NB2;       \
        ls += Pls;                                                  \
        if (RN) CRF_RENORM();                                       \
    } while (0)

    {   // t0: M = D(e) * G
        float e0 = __expf(q0.x), e1 = __expf(q0.y), e2 = __expf(q0.z);
        MA0 = vsplat(e0) * GA0;  MB0 = e0 * GB0;
        MA1 = vsplat(e1) * GA1;  MB1 = e1 * GB1;
        MA2 = vsplat(e2) * GA2;  MB2 = e2 * GB2;
    }
    CRF_STEP(q1.y,  q1.z,  q1.w);    // t1
    CRF_STEP(q2.z,  q2.w,  q3.x);    // t2
    CRF_STEP(q3.w,  q4.x,  q4.y);    // t3
    CRF_STEP(q5.x,  q5.y,  q5.z);    // t4
    CRF_STEP(q6.y,  q6.z,  q6.w);    // t5
    CRF_STEP(q7.z,  q7.w,  q8.x);    // t6
    CRF_STEP(q8.w,  q9.x,  q9.y);    // t7
    CRF_STEP(q10.x, q10.y, q10.z);   // t8
    CRF_STEP(q11.y, q11.z, q11.w);   // t9
    CRF_STEP(q12.z, q12.w, q13.x);   // t10
    CRF_STEP(q13.w, q14.x, q14.y);   // t11
    CRF_STEP(q15.x, q15.y, q15.z);   // t12
    CRF_STEP(q16.y, q16.z, q16.w);   // t13
    CRF_STEP(q17.z, q17.w, q18.x);   // t14
    CRF_STEP(q18.w, q19.x, q19.y);   // t15
    CRF_RENORM();

    // shared tree: lanes 0-31 compose seq A, lanes 32-63 compose seq B.
    // Cross-boundary shfl pollution only reaches lanes whose results are unread.
    TREE_LEVEL(1, 0);
    TREE_LEVEL(2, 0);
    TREE_LEVEL(4, 1);
    TREE_LEVEL(8, 0);
    TREE_LEVEL(16, 1);

    // lanes 0 and 32: column 0 = full product applied to START-init vector.
    // Bias compensation: 512 biased factors * 2.0 = +1024 (exact).
    float r = S0*MA0.x + S1*MA1.x + S2*MA2.x;
    float res = __logf(r) + ls * 0.69314718055994531f + 1024.0f;
    if (cpos == 0) out[s0 + half] = res;

#undef CRF_STEP
#undef CRF_RENORM
#undef TREE_LEVEL
}

extern "C" void kernel_launch(void* const* d_in, const int* in_sizes, int n_in,
                              void* d_out, int out_size, void* d_ws, size_t ws_size,
                              hipStream_t stream) {
    const float* feats = (const float*)d_in[0];
    const float* trans = (const float*)d_in[1];
    float* out = (float*)d_out;
    (void)d_ws; (void)ws_size;

    crf_fused<<<BB / 4, 128, 0, stream>>>(feats, trans, out);
}